// Round 1
// baseline (227.572 us; speedup 1.0000x reference)
//
#include <hip/hip_runtime.h>
#include <hip/hip_bf16.h>

#define B_    8
#define N_    1024
#define DIM_  512
#define H_    8
#define DH_   64
#define SCALE_ 0.125f

typedef __attribute__((ext_vector_type(8))) short bf16x8;
typedef __attribute__((ext_vector_type(4))) float f32x4;

__device__ __forceinline__ unsigned short f2bf(float f) {
  union { float f; unsigned u; } v; v.f = f;
  return (unsigned short)((v.u + 0x7fffu + ((v.u >> 16) & 1u)) >> 16);
}

__device__ __forceinline__ unsigned pack2(float a, float b) {
  return (unsigned)f2bf(a) | ((unsigned)f2bf(b) << 16);
}

// ---------------- Kernel 1: QKV projection ----------------
// C[m][j] = sum_k x[m][k] * qkv_w[j][k];  m = b*N+n, j = t*512 + h*64 + d
// writes Q,K as [B,H,N,D] bf16; V transposed as [B,H,D,N] bf16
__global__ __launch_bounds__(256) void qkv_kernel(
    const float* __restrict__ X, const float* __restrict__ W,
    unsigned short* __restrict__ Q, unsigned short* __restrict__ K,
    unsigned short* __restrict__ Vt) {
  __shared__ __align__(16) short sA[64 * 40];
  __shared__ __align__(16) short sB[64 * 40];
  const int t = threadIdx.x;
  const int wv = t >> 6, lane = t & 63, quad = lane >> 4, l15 = lane & 15;
  const int m0 = blockIdx.y * 64;
  const int j0 = blockIdx.x * 64;

  f32x4 zero = {0.f, 0.f, 0.f, 0.f};
  f32x4 acc[4];
  acc[0] = zero; acc[1] = zero; acc[2] = zero; acc[3] = zero;

  const int r = t >> 2;          // 0..63
  const int c = (t & 3) << 3;    // 0,8,16,24

  for (int k0 = 0; k0 < DIM_; k0 += 32) {
    __syncthreads();
    {
      const float* src = X + (size_t)(m0 + r) * DIM_ + k0 + c;
      float4 f0 = *(const float4*)src;
      float4 f1 = *(const float4*)(src + 4);
      uint4 p;
      p.x = pack2(f0.x, f0.y); p.y = pack2(f0.z, f0.w);
      p.z = pack2(f1.x, f1.y); p.w = pack2(f1.z, f1.w);
      *(uint4*)&sA[r * 40 + c] = p;
      const float* srcB = W + (size_t)(j0 + r) * DIM_ + k0 + c;
      float4 g0 = *(const float4*)srcB;
      float4 g1 = *(const float4*)(srcB + 4);
      uint4 q;
      q.x = pack2(g0.x, g0.y); q.y = pack2(g0.z, g0.w);
      q.z = pack2(g1.x, g1.y); q.w = pack2(g1.z, g1.w);
      *(uint4*)&sB[r * 40 + c] = q;
    }
    __syncthreads();
    bf16x8 a = *(const bf16x8*)&sA[(16 * wv + l15) * 40 + quad * 8];
#pragma unroll
    for (int cb = 0; cb < 4; cb++) {
      bf16x8 bfr = *(const bf16x8*)&sB[(16 * cb + l15) * 40 + quad * 8];
      acc[cb] = __builtin_amdgcn_mfma_f32_16x16x32_bf16(a, bfr, acc[cb], 0, 0, 0);
    }
  }

  const int tsel = j0 >> 9;           // 0=Q, 1=K, 2=V
  const int hh = (j0 & 511) >> 6;     // head (tile is within one head block)
#pragma unroll
  for (int cb = 0; cb < 4; cb++) {
    const int d = cb * 16 + l15;
#pragma unroll
    for (int rr = 0; rr < 4; rr++) {
      const int m = m0 + 16 * wv + quad * 4 + rr;
      const int b = m >> 10, n = m & 1023;
      const unsigned short val = f2bf(acc[cb][rr]);
      if (tsel == 0)      Q[(((size_t)(b * H_ + hh)) * N_ + n) * DH_ + d] = val;
      else if (tsel == 1) K[(((size_t)(b * H_ + hh)) * N_ + n) * DH_ + d] = val;
      else                Vt[(((size_t)(b * H_ + hh)) * DH_ + d) * N_ + n] = val;
    }
  }
}

// ---------------- Kernel 2: flash attention with RPE bias ----------------
// one block = (b,h, 64 query rows); 4 waves, each wave owns 16 q rows
__global__ __launch_bounds__(256) void attn_kernel(
    const unsigned short* __restrict__ Q, const unsigned short* __restrict__ K,
    const unsigned short* __restrict__ Vt, const float* __restrict__ bias,
    unsigned short* __restrict__ Out) {
  __shared__ __align__(16) short sQ[64 * 72];
  __shared__ __align__(16) short sK[64 * 72];
  __shared__ __align__(16) short sV[64 * 72];
  __shared__ __align__(16) short sP[64 * 72];
  const int t = threadIdx.x;
  const int wv = t >> 6, lane = t & 63, quad = lane >> 4, l15 = lane & 15;
  const int n0 = blockIdx.x * 64;
  const int bh = blockIdx.y;
  const int b = bh >> 3, h = bh & 7;

  const int r = t >> 2;          // 0..63
  const int c = (t & 3) << 4;    // 0,16,32,48

  { // stage Q tile once: [64 q][64 d]
    const unsigned short* src = Q + (((size_t)bh * N_) + n0 + r) * DH_ + c;
    uint4 q0 = *(const uint4*)src;
    uint4 q1 = *(const uint4*)(src + 8);
    *(uint4*)&sQ[r * 72 + c] = q0;
    *(uint4*)&sQ[r * 72 + c + 8] = q1;
  }

  f32x4 zero = {0.f, 0.f, 0.f, 0.f};
  f32x4 O[4];
  O[0] = zero; O[1] = zero; O[2] = zero; O[3] = zero;
  float mrow[4], lrow[4];
#pragma unroll
  for (int i = 0; i < 4; i++) { mrow[i] = -1e30f; lrow[i] = 0.f; }

  for (int kt = 0; kt < 16; kt++) {
    const int m0k = kt * 64;
    __syncthreads();
    { // stage K tile [64 key][64 d] and V^T tile [64 d][64 key]
      const unsigned short* srcK = K + (((size_t)bh * N_) + m0k + r) * DH_ + c;
      uint4 k0v = *(const uint4*)srcK;
      uint4 k1v = *(const uint4*)(srcK + 8);
      *(uint4*)&sK[r * 72 + c] = k0v;
      *(uint4*)&sK[r * 72 + c + 8] = k1v;
      const unsigned short* srcV = Vt + (((size_t)bh * DH_) + r) * N_ + m0k + c;
      uint4 v0 = *(const uint4*)srcV;
      uint4 v1 = *(const uint4*)(srcV + 8);
      *(uint4*)&sV[r * 72 + c] = v0;
      *(uint4*)&sV[r * 72 + c + 8] = v1;
    }
    __syncthreads();

    // S = Q Ktile^T : each wave computes its 16 q rows x 64 keys
    f32x4 S[4];
    S[0] = zero; S[1] = zero; S[2] = zero; S[3] = zero;
#pragma unroll
    for (int ks = 0; ks < 2; ks++) {
      bf16x8 a = *(const bf16x8*)&sQ[(16 * wv + l15) * 72 + ks * 32 + quad * 8];
#pragma unroll
      for (int cb = 0; cb < 4; cb++) {
        bf16x8 bb = *(const bf16x8*)&sK[(16 * cb + l15) * 72 + ks * 32 + quad * 8];
        S[cb] = __builtin_amdgcn_mfma_f32_16x16x32_bf16(a, bb, S[cb], 0, 0, 0);
      }
    }

    // scale + rpe bias (fp32)
    float sv[4][4];
#pragma unroll
    for (int cb = 0; cb < 4; cb++) {
      const int kg = m0k + 16 * cb + l15;
#pragma unroll
      for (int rr = 0; rr < 4; rr++) {
        const int qg = n0 + 16 * wv + quad * 4 + rr;
        sv[cb][rr] = S[cb][rr] * SCALE_ + bias[(((size_t)h * N_) + qg) * N_ + kg];
      }
    }

    // online softmax per row (rows live within 16-lane quad groups)
    float pnew[4][4];
#pragma unroll
    for (int rr = 0; rr < 4; rr++) {
      float mx = fmaxf(fmaxf(sv[0][rr], sv[1][rr]), fmaxf(sv[2][rr], sv[3][rr]));
#pragma unroll
      for (int off = 1; off < 16; off <<= 1)
        mx = fmaxf(mx, __shfl_xor(mx, off, 16));
      const float mnew = fmaxf(mrow[rr], mx);
      const float alpha = __expf(mrow[rr] - mnew);
      float rs = 0.f;
#pragma unroll
      for (int cb = 0; cb < 4; cb++) {
        const float p = __expf(sv[cb][rr] - mnew);
        pnew[cb][rr] = p;
        rs += p;
      }
#pragma unroll
      for (int off = 1; off < 16; off <<= 1)
        rs += __shfl_xor(rs, off, 16);
      lrow[rr] = lrow[rr] * alpha + rs;
      mrow[rr] = mnew;
      O[0][rr] *= alpha; O[1][rr] *= alpha; O[2][rr] *= alpha; O[3][rr] *= alpha;
    }

    // write P (D-layout) to LDS, re-read in A-layout for PV
#pragma unroll
    for (int cb = 0; cb < 4; cb++)
#pragma unroll
      for (int rr = 0; rr < 4; rr++)
        sP[(16 * wv + quad * 4 + rr) * 72 + 16 * cb + l15] = (short)f2bf(pnew[cb][rr]);
    __syncthreads();

#pragma unroll
    for (int ks = 0; ks < 2; ks++) {
      bf16x8 a = *(const bf16x8*)&sP[(16 * wv + l15) * 72 + ks * 32 + quad * 8];
#pragma unroll
      for (int cb = 0; cb < 4; cb++) {
        bf16x8 bb = *(const bf16x8*)&sV[(16 * cb + l15) * 72 + ks * 32 + quad * 8];
        O[cb] = __builtin_amdgcn_mfma_f32_16x16x32_bf16(a, bb, O[cb], 0, 0, 0);
      }
    }
  }

  // epilogue: O/l -> attnout [B,N,C] bf16, c = h*64 + d
#pragma unroll
  for (int cb = 0; cb < 4; cb++)
#pragma unroll
    for (int rr = 0; rr < 4; rr++) {
      const int qg = n0 + 16 * wv + quad * 4 + rr;
      const float o = O[cb][rr] / lrow[rr];
      Out[(((size_t)b * N_) + qg) * DIM_ + h * DH_ + 16 * cb + l15] = f2bf(o);
    }
}

// ---------------- Kernel 3: output projection + bias ----------------
__global__ __launch_bounds__(256) void proj_kernel(
    const unsigned short* __restrict__ A, const float* __restrict__ W,
    const float* __restrict__ Pb, float* __restrict__ Out) {
  __shared__ __align__(16) short sA[64 * 40];
  __shared__ __align__(16) short sB[64 * 40];
  const int t = threadIdx.x;
  const int wv = t >> 6, lane = t & 63, quad = lane >> 4, l15 = lane & 15;
  const int m0 = blockIdx.y * 64;
  const int j0 = blockIdx.x * 64;

  f32x4 zero = {0.f, 0.f, 0.f, 0.f};
  f32x4 acc[4];
  acc[0] = zero; acc[1] = zero; acc[2] = zero; acc[3] = zero;

  const int r = t >> 2;
  const int c = (t & 3) << 3;

  for (int k0 = 0; k0 < DIM_; k0 += 32) {
    __syncthreads();
    {
      // A tile: bf16 source, direct copy
      const unsigned short* src = A + (size_t)(m0 + r) * DIM_ + k0 + c;
      *(uint4*)&sA[r * 40 + c] = *(const uint4*)src;
      // B tile: fp32 -> bf16
      const float* srcB = W + (size_t)(j0 + r) * DIM_ + k0 + c;
      float4 g0 = *(const float4*)srcB;
      float4 g1 = *(const float4*)(srcB + 4);
      uint4 q;
      q.x = pack2(g0.x, g0.y); q.y = pack2(g0.z, g0.w);
      q.z = pack2(g1.x, g1.y); q.w = pack2(g1.z, g1.w);
      *(uint4*)&sB[r * 40 + c] = q;
    }
    __syncthreads();
    bf16x8 a = *(const bf16x8*)&sA[(16 * wv + l15) * 40 + quad * 8];
#pragma unroll
    for (int cb = 0; cb < 4; cb++) {
      bf16x8 bfr = *(const bf16x8*)&sB[(16 * cb + l15) * 40 + quad * 8];
      acc[cb] = __builtin_amdgcn_mfma_f32_16x16x32_bf16(a, bfr, acc[cb], 0, 0, 0);
    }
  }

#pragma unroll
  for (int cb = 0; cb < 4; cb++) {
    const int j = j0 + 16 * cb + l15;
    const float pb = Pb[j];
#pragma unroll
    for (int rr = 0; rr < 4; rr++) {
      const int m = m0 + 16 * wv + quad * 4 + rr;
      Out[(size_t)m * DIM_ + j] = acc[cb][rr] + pb;
    }
  }
}

extern "C" void kernel_launch(void* const* d_in, const int* in_sizes, int n_in,
                              void* d_out, int out_size, void* d_ws, size_t ws_size,
                              hipStream_t stream) {
  const float* x      = (const float*)d_in[0];
  const float* rpe    = (const float*)d_in[1];
  const float* qkv_w  = (const float*)d_in[2];
  const float* proj_w = (const float*)d_in[3];
  const float* proj_b = (const float*)d_in[4];
  float* out = (float*)d_out;

  const size_t perbuf = (size_t)B_ * H_ * N_ * DH_;  // 4,194,304 elems
  unsigned short* Q  = (unsigned short*)d_ws;
  unsigned short* K  = Q + perbuf;
  unsigned short* Vt = K + perbuf;
  unsigned short* AO = Vt + perbuf;   // attention out [B,N,C] bf16

  qkv_kernel<<<dim3(24, 128), 256, 0, stream>>>(x, qkv_w, Q, K, Vt);
  attn_kernel<<<dim3(16, 64), 256, 0, stream>>>(Q, K, Vt, rpe, AO);
  proj_kernel<<<dim3(8, 128), 256, 0, stream>>>(AO, proj_w, proj_b, out);
}

// Round 2
// 182.274 us; speedup vs baseline: 1.2485x; 1.2485x over previous
//
#include <hip/hip_runtime.h>
#include <hip/hip_bf16.h>

#define B_    8
#define N_    1024
#define DIM_  512
#define H_    8
#define DH_   64
#define SCALE_ 0.125f

typedef unsigned short u16;
typedef __attribute__((ext_vector_type(8))) short bf16x8;
typedef __attribute__((ext_vector_type(4))) float f32x4;

__device__ __forceinline__ u16 f2bf(float f) {
  union { float f; unsigned u; } v; v.f = f;
  return (u16)((v.u + 0x7fffu + ((v.u >> 16) & 1u)) >> 16);
}
__device__ __forceinline__ unsigned pack2(float a, float b) {
  return (unsigned)f2bf(a) | ((unsigned)f2bf(b) << 16);
}
__device__ __forceinline__ void cp16(const void* g, void* l) {
  __builtin_amdgcn_global_load_lds(
      (const __attribute__((address_space(1))) unsigned*)g,
      (__attribute__((address_space(3))) unsigned*)l, 16, 0, 0);
}

// ---------------- Kernel 0: fp32 -> bf16 convert (X, qkv_w, proj_w) --------
__global__ __launch_bounds__(256) void convert_kernel(
    const float* __restrict__ X, const float* __restrict__ Wq,
    const float* __restrict__ Wp, u16* __restrict__ Xb,
    u16* __restrict__ Wqb, u16* __restrict__ Wpb) {
  const int NX4 = (B_ * N_ * DIM_) / 4;        // 1048576
  const int NQ4 = (3 * DIM_ * DIM_) / 4;       // 196608
  const int NP4 = (DIM_ * DIM_) / 4;           // 65536
  const int total = NX4 + NQ4 + NP4;
  const int stride = gridDim.x * 256;
  for (int i = blockIdx.x * 256 + threadIdx.x; i < total; i += stride) {
    const float* s; u16* d; int off;
    if (i < NX4)            { s = X;  d = Xb;  off = i; }
    else if (i < NX4 + NQ4) { s = Wq; d = Wqb; off = i - NX4; }
    else                    { s = Wp; d = Wpb; off = i - NX4 - NQ4; }
    float4 f = *(const float4*)(s + (size_t)off * 4);
    uint2 u; u.x = pack2(f.x, f.y); u.y = pack2(f.z, f.w);
    *(uint2*)(d + (size_t)off * 4) = u;
  }
}

// ---------------- Kernel 1: QKV GEMM 128x128 tile, global_load_lds ---------
// C[m][j] = sum_k Xb[m][k] * Wqb[j][k]; scatter to Q,K [bh][n][d], Vt [bh][d][n]
__global__ __launch_bounds__(256) void qkv_gemm(
    const u16* __restrict__ Ab, const u16* __restrict__ Bb,
    u16* __restrict__ Q, u16* __restrict__ K, u16* __restrict__ Vt) {
  __shared__ __align__(16) u16 sA[128 * 64];
  __shared__ __align__(16) u16 sB[128 * 64];
  const int t = threadIdx.x;
  const int wv = t >> 6, lane = t & 63, quad = (lane >> 4) & 3, l15 = lane & 15;
  const int wr = wv >> 1, wc = wv & 1;
  const int m0 = blockIdx.y * 128;
  const int n0 = blockIdx.x * 128;

  const int srow = lane >> 3;                 // 0..7
  const int schunk = (lane & 7) ^ srow;       // xor-swizzled source chunk
  const size_t ga = (size_t)(m0 + srow) * DIM_ + schunk * 8;
  const size_t gb = (size_t)(n0 + srow) * DIM_ + schunk * 8;

  f32x4 zero = {0.f, 0.f, 0.f, 0.f};
  f32x4 acc[4][4];
#pragma unroll
  for (int i = 0; i < 4; i++)
#pragma unroll
    for (int j = 0; j < 4; j++) acc[i][j] = zero;

  for (int k0 = 0; k0 < DIM_; k0 += 64) {
    __syncthreads();
#pragma unroll
    for (int i = 0; i < 4; i++) {
      const int rb = 32 * wv + 8 * i;
      cp16(Ab + ga + (size_t)rb * DIM_ + k0, &sA[rb * 64]);
      cp16(Bb + gb + (size_t)rb * DIM_ + k0, &sB[rb * 64]);
    }
    __syncthreads();
#pragma unroll
    for (int ks = 0; ks < 2; ks++) {
      bf16x8 af[4], bfv[4];
#pragma unroll
      for (int i = 0; i < 4; i++)
        af[i] = *(const bf16x8*)&sA[(wr * 64 + 16 * i + l15) * 64 +
                                    (((ks << 2) | quad) ^ (l15 & 7)) * 8];
#pragma unroll
      for (int j = 0; j < 4; j++)
        bfv[j] = *(const bf16x8*)&sB[(wc * 64 + 16 * j + l15) * 64 +
                                     (((ks << 2) | quad) ^ (l15 & 7)) * 8];
#pragma unroll
      for (int i = 0; i < 4; i++)
#pragma unroll
        for (int j = 0; j < 4; j++)
          acc[i][j] = __builtin_amdgcn_mfma_f32_16x16x32_bf16(af[i], bfv[j], acc[i][j], 0, 0, 0);
    }
  }

  const int tsel = n0 >> 9;   // 0=Q,1=K,2=V (128 | 512 boundaries)
#pragma unroll
  for (int j = 0; j < 4; j++) {
    const int jg = n0 + wc * 64 + 16 * j + l15;
    const int h = (jg >> 6) & 7, d = jg & 63;
#pragma unroll
    for (int i = 0; i < 4; i++) {
      const int mbase = m0 + wr * 64 + 16 * i + quad * 4;
      const int b = mbase >> 10, nb = mbase & 1023;
      const size_t bh = (size_t)(b * H_ + h);
      if (tsel == 2) {
        ushort4 v4;
        v4.x = f2bf(acc[i][j][0]); v4.y = f2bf(acc[i][j][1]);
        v4.z = f2bf(acc[i][j][2]); v4.w = f2bf(acc[i][j][3]);
        *(ushort4*)&Vt[(bh * DH_ + d) * N_ + nb] = v4;
      } else {
        u16* dst = (tsel == 0 ? Q : K);
#pragma unroll
        for (int rr = 0; rr < 4; rr++)
          dst[(bh * N_ + nb + rr) * DH_ + d] = f2bf(acc[i][j][rr]);
      }
    }
  }
}

// ---------------- Kernel 2: flash attention, S^T formulation ----------------
__global__ __launch_bounds__(256) void attn_kernel(
    const u16* __restrict__ Q, const u16* __restrict__ K,
    const u16* __restrict__ Vt, const float* __restrict__ bias,
    u16* __restrict__ AO) {
  __shared__ __align__(16) u16 sQ[64 * 72];
  __shared__ __align__(16) u16 sK[64 * 72];
  __shared__ __align__(16) u16 sV[64 * 72];
  __shared__ __align__(16) u16 sP[64 * 72];
  const int t = threadIdx.x;
  const int wv = t >> 6, lane = t & 63, quad = (lane >> 4) & 3, l15 = lane & 15;
  const int n0 = blockIdx.x * 64;
  const int bh = blockIdx.y;
  const int b = bh >> 3, h = bh & 7;
  const int r = t >> 2, c = (t & 3) << 4;

  { // stage Q tile once [64 q][64 d]
    const u16* src = Q + (((size_t)bh << 10) + n0 + r) * DH_ + c;
    *(uint4*)&sQ[r * 72 + c] = *(const uint4*)src;
    *(uint4*)&sQ[r * 72 + c + 8] = *(const uint4*)(src + 8);
  }

  const int qg = n0 + 16 * wv + l15;
  const float* bp = bias + (((size_t)h << 10) + qg) * N_ + (quad << 2);
  const u16* kbase = K + (((size_t)bh << 10) + r) * DH_ + c;
  const u16* vbase = Vt + (((size_t)bh << 6) + r) * N_ + c;

  f32x4 zero = {0.f, 0.f, 0.f, 0.f};
  f32x4 O[4];
  O[0] = zero; O[1] = zero; O[2] = zero; O[3] = zero;
  float mrow = -1e30f, lrow = 0.f;

  for (int kt = 0; kt < 16; kt++) {
    const int m0k = kt << 6;
    __syncthreads();
    {
      const u16* sk = kbase + (size_t)m0k * DH_;
      uint4 a0 = *(const uint4*)sk, a1 = *(const uint4*)(sk + 8);
      const u16* svp = vbase + m0k;
      uint4 b0 = *(const uint4*)svp, b1 = *(const uint4*)(svp + 8);
      *(uint4*)&sK[r * 72 + c] = a0; *(uint4*)&sK[r * 72 + c + 8] = a1;
      *(uint4*)&sV[r * 72 + c] = b0; *(uint4*)&sV[r * 72 + c + 8] = b1;
    }
    float4 bias4[4];
#pragma unroll
    for (int cb = 0; cb < 4; cb++) bias4[cb] = *(const float4*)(bp + m0k + 16 * cb);
    __syncthreads();

    // S^T[key][q] = K . Q^T  (A = K rows, B = Q rows)
    f32x4 S[4];
    S[0] = zero; S[1] = zero; S[2] = zero; S[3] = zero;
#pragma unroll
    for (int ks = 0; ks < 2; ks++) {
      bf16x8 qf = *(const bf16x8*)&sQ[(16 * wv + l15) * 72 + ks * 32 + quad * 8];
#pragma unroll
      for (int cb = 0; cb < 4; cb++) {
        bf16x8 kf = *(const bf16x8*)&sK[(16 * cb + l15) * 72 + ks * 32 + quad * 8];
        S[cb] = __builtin_amdgcn_mfma_f32_16x16x32_bf16(kf, qf, S[cb], 0, 0, 0);
      }
    }

    // scale + bias (key = m0k+16cb+quad*4+rr, q = qg -- one q per lane)
    float sv4[4][4];
    float mx = -1e30f;
#pragma unroll
    for (int cb = 0; cb < 4; cb++) {
      sv4[cb][0] = S[cb][0] * SCALE_ + bias4[cb].x;
      sv4[cb][1] = S[cb][1] * SCALE_ + bias4[cb].y;
      sv4[cb][2] = S[cb][2] * SCALE_ + bias4[cb].z;
      sv4[cb][3] = S[cb][3] * SCALE_ + bias4[cb].w;
      mx = fmaxf(mx, fmaxf(fmaxf(sv4[cb][0], sv4[cb][1]), fmaxf(sv4[cb][2], sv4[cb][3])));
    }
    mx = fmaxf(mx, __shfl_xor(mx, 16));
    mx = fmaxf(mx, __shfl_xor(mx, 32));
    const float mnew = fmaxf(mrow, mx);
    const float alpha = __expf(mrow - mnew);
    float rs = 0.f;
#pragma unroll
    for (int cb = 0; cb < 4; cb++)
#pragma unroll
      for (int rr = 0; rr < 4; rr++) {
        sv4[cb][rr] = __expf(sv4[cb][rr] - mnew);
        rs += sv4[cb][rr];
      }
    rs += __shfl_xor(rs, 16);
    rs += __shfl_xor(rs, 32);
    lrow = lrow * alpha + rs;
    mrow = mnew;
#pragma unroll
    for (int cb = 0; cb < 4; cb++) {
      O[cb][0] *= alpha; O[cb][1] *= alpha; O[cb][2] *= alpha; O[cb][3] *= alpha;
    }

    // write P^T rows (per-wave region of sP, no block barrier needed)
#pragma unroll
    for (int cb = 0; cb < 4; cb++) {
      uint2 pk;
      pk.x = pack2(sv4[cb][0], sv4[cb][1]);
      pk.y = pack2(sv4[cb][2], sv4[cb][3]);
      *(uint2*)&sP[(16 * wv + l15) * 72 + 16 * cb + (quad << 2)] = pk;
    }
    asm volatile("s_waitcnt lgkmcnt(0)" ::: "memory");

    // O^T[d][q] += V^T . P^T  (A = Vt rows (d), B = P rows (q))
#pragma unroll
    for (int ks = 0; ks < 2; ks++) {
      bf16x8 pf = *(const bf16x8*)&sP[(16 * wv + l15) * 72 + ks * 32 + quad * 8];
#pragma unroll
      for (int cb = 0; cb < 4; cb++) {
        bf16x8 vf = *(const bf16x8*)&sV[(16 * cb + l15) * 72 + ks * 32 + quad * 8];
        O[cb] = __builtin_amdgcn_mfma_f32_16x16x32_bf16(vf, pf, O[cb], 0, 0, 0);
      }
    }
  }

  const float inv = 1.f / lrow;
#pragma unroll
  for (int cb = 0; cb < 4; cb++) {
    ushort4 o4;
    o4.x = f2bf(O[cb][0] * inv); o4.y = f2bf(O[cb][1] * inv);
    o4.z = f2bf(O[cb][2] * inv); o4.w = f2bf(O[cb][3] * inv);
    *(ushort4*)&AO[(((size_t)b << 10) + qg) * DIM_ + h * DH_ + 16 * cb + (quad << 2)] = o4;
  }
}

// ---------------- Kernel 3: output projection 128x128 tile ------------------
__global__ __launch_bounds__(256) void proj_gemm(
    const u16* __restrict__ Ab, const u16* __restrict__ Bb,
    const float* __restrict__ Pb, float* __restrict__ Out) {
  __shared__ __align__(16) u16 sA[128 * 64];
  __shared__ __align__(16) u16 sB[128 * 64];
  const int t = threadIdx.x;
  const int wv = t >> 6, lane = t & 63, quad = (lane >> 4) & 3, l15 = lane & 15;
  const int wr = wv >> 1, wc = wv & 1;
  const int m0 = blockIdx.y * 128;
  const int n0 = blockIdx.x * 128;

  const int srow = lane >> 3;
  const int schunk = (lane & 7) ^ srow;
  const size_t ga = (size_t)(m0 + srow) * DIM_ + schunk * 8;
  const size_t gb = (size_t)(n0 + srow) * DIM_ + schunk * 8;

  f32x4 zero = {0.f, 0.f, 0.f, 0.f};
  f32x4 acc[4][4];
#pragma unroll
  for (int i = 0; i < 4; i++)
#pragma unroll
    for (int j = 0; j < 4; j++) acc[i][j] = zero;

  for (int k0 = 0; k0 < DIM_; k0 += 64) {
    __syncthreads();
#pragma unroll
    for (int i = 0; i < 4; i++) {
      const int rb = 32 * wv + 8 * i;
      cp16(Ab + ga + (size_t)rb * DIM_ + k0, &sA[rb * 64]);
      cp16(Bb + gb + (size_t)rb * DIM_ + k0, &sB[rb * 64]);
    }
    __syncthreads();
#pragma unroll
    for (int ks = 0; ks < 2; ks++) {
      bf16x8 af[4], bfv[4];
#pragma unroll
      for (int i = 0; i < 4; i++)
        af[i] = *(const bf16x8*)&sA[(wr * 64 + 16 * i + l15) * 64 +
                                    (((ks << 2) | quad) ^ (l15 & 7)) * 8];
#pragma unroll
      for (int j = 0; j < 4; j++)
        bfv[j] = *(const bf16x8*)&sB[(wc * 64 + 16 * j + l15) * 64 +
                                     (((ks << 2) | quad) ^ (l15 & 7)) * 8];
#pragma unroll
      for (int i = 0; i < 4; i++)
#pragma unroll
        for (int j = 0; j < 4; j++)
          acc[i][j] = __builtin_amdgcn_mfma_f32_16x16x32_bf16(af[i], bfv[j], acc[i][j], 0, 0, 0);
    }
  }

#pragma unroll
  for (int j = 0; j < 4; j++) {
    const int jg = n0 + wc * 64 + 16 * j + l15;
    const float pb = Pb[jg];
#pragma unroll
    for (int i = 0; i < 4; i++) {
      const int mbase = m0 + wr * 64 + 16 * i + quad * 4;
#pragma unroll
      for (int rr = 0; rr < 4; rr++)
        Out[(size_t)(mbase + rr) * DIM_ + jg] = acc[i][j][rr] + pb;
    }
  }
}

extern "C" void kernel_launch(void* const* d_in, const int* in_sizes, int n_in,
                              void* d_out, int out_size, void* d_ws, size_t ws_size,
                              hipStream_t stream) {
  const float* x      = (const float*)d_in[0];
  const float* rpe    = (const float*)d_in[1];
  const float* qkv_w  = (const float*)d_in[2];
  const float* proj_w = (const float*)d_in[3];
  const float* proj_b = (const float*)d_in[4];
  float* out = (float*)d_out;

  const size_t perbuf = (size_t)B_ * N_ * DIM_;   // 4,194,304
  u16* Xb  = (u16*)d_ws;          // aliased with AO (lifetimes disjoint)
  u16* Q   = Xb + perbuf;
  u16* K   = Q + perbuf;
  u16* Vt  = K + perbuf;
  u16* Wqb = Vt + perbuf;         // 786,432
  u16* Wpb = Wqb + (size_t)3 * DIM_ * DIM_;  // 262,144
  u16* AO  = Xb;

  convert_kernel<<<2560, 256, 0, stream>>>(x, qkv_w, proj_w, Xb, Wqb, Wpb);
  qkv_gemm<<<dim3(12, 64), 256, 0, stream>>>(Xb, Wqb, Q, K, Vt);
  attn_kernel<<<dim3(16, 64), 256, 0, stream>>>(Q, K, Vt, rpe, AO);
  proj_gemm<<<dim3(4, 64), 256, 0, stream>>>(AO, Wpb, proj_b, out);
}